// Round 8
// baseline (207.643 us; speedup 1.0000x reference)
//
#include <hip/hip_runtime.h>
#include <hip/hip_bf16.h>

typedef __attribute__((ext_vector_type(8))) __bf16 bf16x8;
typedef __attribute__((ext_vector_type(4))) float f32x4;
typedef __attribute__((ext_vector_type(4))) unsigned int u32x4;
typedef unsigned long long ull;

#define NB 16
#define CIN 32
#define COUT 64
#define HW 224
#define HWHW (HW * HW)          // 50176
#define CHW (CIN * HW * HW)     // 1605632

__device__ __forceinline__ unsigned short f2bf(float f) {
    __hip_bfloat16 h = __float2bfloat16(f);
    return __builtin_bit_cast(unsigned short, h);
}

// ---- K1: weight OIHW fp32 -> wT[co][tap][cin] bf16 (64*9*32 = 18432) ----
__global__ void k_wxform(const float* __restrict__ w, unsigned short* __restrict__ wT) {
    int i = blockIdx.x * 256 + threadIdx.x;
    if (i >= COUT * 9 * CIN) return;
    int co = i / (9 * CIN);
    int r  = i % (9 * CIN);
    int tap = r / CIN;
    int c   = r % CIN;
    wT[i] = f2bf(w[(co * CIN + c) * 9 + tap]);
}

// ---- K2: fused conv, register-gather (no LDS, no barriers). One block per
// (b,h); 4 waves x (64px x 64cout). 288 independent scalar loads per thread
// feed bf16 MFMA fragments directly; occupancy 4 waves/EU hides latency. ----
__global__ __launch_bounds__(256, 4)
void k_fused(const float* __restrict__ x, const unsigned short* __restrict__ wT,
             const float* __restrict__ bias, float* __restrict__ out) {
    int bid = blockIdx.x;
    int wg  = (bid & 7) * 448 + (bid >> 3);   // XCD-chunked swizzle, 3584 = 8*448
    int b = wg / HW, h = wg % HW;
    int wave = threadIdx.x >> 6, lane = threadIdx.x & 63;
    int r = lane & 15;                // A-row (pixel local) / B-col (cout local)
    int q = lane >> 4;
    int chunk = q * 8;                // k sub-chunk (cin)
    const float* xb = x + (ull)b * CHW + (ull)chunk * HWHW;

    int pc[4];
    #pragma unroll
    for (int pf = 0; pf < 4; ++pf) {
        int px = wave * 64 + pf * 16 + r;
        pc[pf] = px < HW ? px : HW - 1;   // clamp masked tail (wave 3) into bounds
    }

    f32x4 acc[4][4];
    #pragma unroll
    for (int i = 0; i < 4; ++i)
        #pragma unroll
        for (int j = 0; j < 4; ++j) acc[i][j] = (f32x4){0.f, 0.f, 0.f, 0.f};

    #pragma unroll
    for (int dh = 0; dh < 3; ++dh) {
        int hy = h + dh - 1;
        if (hy >= 0 && hy < HW) {         // block-uniform branch (h-pad)
            const float* xrow = xb + (ull)hy * HW;
            #pragma unroll
            for (int dw = 0; dw < 3; ++dw) {
                int tap = dh * 3 + dw;
                bf16x8 wf[4];
                #pragma unroll
                for (int cf = 0; cf < 4; ++cf)
                    wf[cf] = *reinterpret_cast<const bf16x8*>(wT + (cf * 16 + r) * 288 + tap * 32 + chunk);
                bf16x8 xf[4];
                #pragma unroll
                for (int pf = 0; pf < 4; ++pf) {
                    int wx = pc[pf] + dw - 1;
                    bool valid = ((unsigned)wx < (unsigned)HW);   // w-pad -> zero
                    int wxc = valid ? wx : 0;
                    const float* p = xrow + wxc;
                    unsigned int pk0, pk1, pk2, pk3;
                    {
                        float f0 = p[0 * HWHW], f1 = p[1 * HWHW];
                        float f2 = p[2 * HWHW], f3 = p[3 * HWHW];
                        float f4 = p[4 * HWHW], f5 = p[5 * HWHW];
                        float f6 = p[6 * HWHW], f7 = p[7 * HWHW];
                        pk0 = (unsigned)f2bf(f0) | ((unsigned)f2bf(f1) << 16);
                        pk1 = (unsigned)f2bf(f2) | ((unsigned)f2bf(f3) << 16);
                        pk2 = (unsigned)f2bf(f4) | ((unsigned)f2bf(f5) << 16);
                        pk3 = (unsigned)f2bf(f6) | ((unsigned)f2bf(f7) << 16);
                    }
                    unsigned int zmask = valid ? 0xFFFFFFFFu : 0u;
                    u32x4 t = (u32x4){pk0 & zmask, pk1 & zmask, pk2 & zmask, pk3 & zmask};
                    xf[pf] = __builtin_bit_cast(bf16x8, t);
                }
                #pragma unroll
                for (int cf = 0; cf < 4; ++cf)
                    #pragma unroll
                    for (int pf = 0; pf < 4; ++pf)
                        acc[cf][pf] = __builtin_amdgcn_mfma_f32_16x16x32_bf16(xf[pf], wf[cf], acc[cf][pf], 0, 0, 0);
            }
        }
    }

    // epilogue: D row = pixel = q*4+reg, col = cout = lane&15; NORMAL stores
    // (16 cout-rows x 64B contiguous per instr -> L2 write-combines to full lines).
    #pragma unroll
    for (int cf = 0; cf < 4; ++cf) {
        int co = cf * 16 + r;
        float bv = bias[co];
        float* orow = out + ((ull)(b * COUT + co) * HW + h) * HW;
        #pragma unroll
        for (int pf = 0; pf < 4; ++pf) {
            int pxb = wave * 64 + pf * 16;
            if (pxb < HW) {                  // frag fully valid or fully masked
                int px0 = pxb + q * 4;
                *reinterpret_cast<f32x4*>(orow + px0) = acc[cf][pf] + bv;
            }
        }
    }
}

// ---- fallback: naive direct fp32 conv (used only if ws too small) ----
__global__ void k_naive(const float* __restrict__ x, const float* __restrict__ w,
                        const float* __restrict__ bias, float* __restrict__ out, long long n) {
    long long i = (long long)blockIdx.x * 256 + threadIdx.x;
    if (i >= n) return;
    int wc = i % HW; long long t = i / HW;
    int h = t % HW; t /= HW;
    int co = t % COUT; int b = (int)(t / COUT);
    float s = bias[co];
    for (int c = 0; c < CIN; ++c)
        for (int dh = 0; dh < 3; ++dh) {
            int hy = h + dh - 1; if (hy < 0 || hy >= HW) continue;
            for (int dw = 0; dw < 3; ++dw) {
                int wx = wc + dw - 1; if (wx < 0 || wx >= HW) continue;
                s += x[(((long long)b * CIN + c) * HW + hy) * HW + wx] *
                     w[((co * CIN + c) * 3 + dh) * 3 + dw];
            }
        }
    out[i] = s;
}

extern "C" void kernel_launch(void* const* d_in, const int* in_sizes, int n_in,
                              void* d_out, int out_size, void* d_ws, size_t ws_size,
                              hipStream_t stream) {
    const float* x    = (const float*)d_in[0];
    const float* w    = (const float*)d_in[1];
    const float* bias = (const float*)d_in[2];
    float* out = (float*)d_out;

    if (ws_size < (size_t)(COUT * 9 * CIN * 2 + 1024)) {
        long long n = (long long)NB * COUT * HW * HW;
        k_naive<<<(int)((n + 255) / 256), 256, 0, stream>>>(x, w, bias, out, n);
        return;
    }
    unsigned short* wT = (unsigned short*)d_ws;

    k_wxform<<<72, 256, 0, stream>>>(w, wT);
    k_fused<<<NB * HW, 256, 0, stream>>>(x, wT, bias, out);
}

// Round 9
// 142.263 us; speedup vs baseline: 1.4596x; 1.4596x over previous
//
#include <hip/hip_runtime.h>
#include <hip/hip_bf16.h>

typedef __attribute__((ext_vector_type(8))) __bf16 bf16x8;
typedef __attribute__((ext_vector_type(4))) float f32x4;
typedef __attribute__((ext_vector_type(4))) unsigned int u32x4;
typedef unsigned long long ull;

#define NB 16
#define CIN 32
#define COUT 64
#define HW 224
#define HWHW (HW * HW)          // 50176
#define CHW (CIN * HW * HW)     // 1605632

__device__ __forceinline__ unsigned short f2bf(float f) {
    __hip_bfloat16 h = __float2bfloat16(f);
    return __builtin_bit_cast(unsigned short, h);
}

// ---- K1: weight OIHW fp32 -> wT[co][tap][cin] bf16 (64*9*32 = 18432) ----
__global__ void k_wxform(const float* __restrict__ w, unsigned short* __restrict__ wT) {
    int i = blockIdx.x * 256 + threadIdx.x;
    if (i >= COUT * 9 * CIN) return;
    int co = i / (9 * CIN);
    int r  = i % (9 * CIN);
    int tap = r / CIN;
    int c   = r % CIN;
    wT[i] = f2bf(w[(co * CIN + c) * 9 + tap]);
}

// ---- K2: fused conv, register-gather (no LDS, no barriers). One block per
// (b,h); 4 waves x (64px x 64cout). 288 independent scalar loads per thread
// feed bf16 MFMA fragments directly. 3 waves/EU keeps a 128-VGPR budget for
// deep load pipelining (4/EU forced VGPR=64 and regressed: round 8). ----
__global__ __launch_bounds__(256, 3)
void k_fused(const float* __restrict__ x, const unsigned short* __restrict__ wT,
             const float* __restrict__ bias, float* __restrict__ out) {
    int bid = blockIdx.x;
    int wg  = (bid & 7) * 448 + (bid >> 3);   // XCD-chunked swizzle, 3584 = 8*448
    int b = wg / HW, h = wg % HW;
    int wave = threadIdx.x >> 6, lane = threadIdx.x & 63;
    int r = lane & 15;                // A-row (pixel local) / B-col (cout local)
    int q = lane >> 4;
    int chunk = q * 8;                // k sub-chunk (cin)
    const float* xb = x + (ull)b * CHW + (ull)chunk * HWHW;

    int pc[4];
    #pragma unroll
    for (int pf = 0; pf < 4; ++pf) {
        int px = wave * 64 + pf * 16 + r;
        pc[pf] = px < HW ? px : HW - 1;   // clamp masked tail (wave 3) into bounds
    }

    f32x4 acc[4][4];
    #pragma unroll
    for (int i = 0; i < 4; ++i)
        #pragma unroll
        for (int j = 0; j < 4; ++j) acc[i][j] = (f32x4){0.f, 0.f, 0.f, 0.f};

    #pragma unroll
    for (int dh = 0; dh < 3; ++dh) {
        int hy = h + dh - 1;
        if (hy >= 0 && hy < HW) {         // block-uniform branch (h-pad)
            const float* xrow = xb + (ull)hy * HW;
            #pragma unroll
            for (int dw = 0; dw < 3; ++dw) {
                int tap = dh * 3 + dw;
                bf16x8 wf[4];
                #pragma unroll
                for (int cf = 0; cf < 4; ++cf)
                    wf[cf] = *reinterpret_cast<const bf16x8*>(wT + (cf * 16 + r) * 288 + tap * 32 + chunk);
                bf16x8 xf[4];
                #pragma unroll
                for (int pf = 0; pf < 4; ++pf) {
                    int wx = pc[pf] + dw - 1;
                    bool valid = ((unsigned)wx < (unsigned)HW);   // w-pad -> zero
                    int wxc = valid ? wx : 0;
                    const float* p = xrow + wxc;
                    unsigned int pk0, pk1, pk2, pk3;
                    {
                        float f0 = p[0 * HWHW], f1 = p[1 * HWHW];
                        float f2 = p[2 * HWHW], f3 = p[3 * HWHW];
                        float f4 = p[4 * HWHW], f5 = p[5 * HWHW];
                        float f6 = p[6 * HWHW], f7 = p[7 * HWHW];
                        pk0 = (unsigned)f2bf(f0) | ((unsigned)f2bf(f1) << 16);
                        pk1 = (unsigned)f2bf(f2) | ((unsigned)f2bf(f3) << 16);
                        pk2 = (unsigned)f2bf(f4) | ((unsigned)f2bf(f5) << 16);
                        pk3 = (unsigned)f2bf(f6) | ((unsigned)f2bf(f7) << 16);
                    }
                    unsigned int zmask = valid ? 0xFFFFFFFFu : 0u;
                    u32x4 t = (u32x4){pk0 & zmask, pk1 & zmask, pk2 & zmask, pk3 & zmask};
                    xf[pf] = __builtin_bit_cast(bf16x8, t);
                }
                #pragma unroll
                for (int cf = 0; cf < 4; ++cf)
                    #pragma unroll
                    for (int pf = 0; pf < 4; ++pf)
                        acc[cf][pf] = __builtin_amdgcn_mfma_f32_16x16x32_bf16(xf[pf], wf[cf], acc[cf][pf], 0, 0, 0);
            }
        }
    }

    // epilogue: D row = pixel = q*4+reg, col = cout = lane&15; NORMAL stores
    // (nt stores defeated L2 write-combining: +95MB WRITE, rounds 5 vs 6/7).
    #pragma unroll
    for (int cf = 0; cf < 4; ++cf) {
        int co = cf * 16 + r;
        float bv = bias[co];
        float* orow = out + ((ull)(b * COUT + co) * HW + h) * HW;
        #pragma unroll
        for (int pf = 0; pf < 4; ++pf) {
            int pxb = wave * 64 + pf * 16;
            if (pxb < HW) {                  // frag fully valid or fully masked
                int px0 = pxb + q * 4;
                *reinterpret_cast<f32x4*>(orow + px0) = acc[cf][pf] + bv;
            }
        }
    }
}

// ---- fallback: naive direct fp32 conv (used only if ws too small) ----
__global__ void k_naive(const float* __restrict__ x, const float* __restrict__ w,
                        const float* __restrict__ bias, float* __restrict__ out, long long n) {
    long long i = (long long)blockIdx.x * 256 + threadIdx.x;
    if (i >= n) return;
    int wc = i % HW; long long t = i / HW;
    int h = t % HW; t /= HW;
    int co = t % COUT; int b = (int)(t / COUT);
    float s = bias[co];
    for (int c = 0; c < CIN; ++c)
        for (int dh = 0; dh < 3; ++dh) {
            int hy = h + dh - 1; if (hy < 0 || hy >= HW) continue;
            for (int dw = 0; dw < 3; ++dw) {
                int wx = wc + dw - 1; if (wx < 0 || wx >= HW) continue;
                s += x[(((long long)b * CIN + c) * HW + hy) * HW + wx] *
                     w[((co * CIN + c) * 3 + dh) * 3 + dw];
            }
        }
    out[i] = s;
}

extern "C" void kernel_launch(void* const* d_in, const int* in_sizes, int n_in,
                              void* d_out, int out_size, void* d_ws, size_t ws_size,
                              hipStream_t stream) {
    const float* x    = (const float*)d_in[0];
    const float* w    = (const float*)d_in[1];
    const float* bias = (const float*)d_in[2];
    float* out = (float*)d_out;

    if (ws_size < (size_t)(COUT * 9 * CIN * 2 + 1024)) {
        long long n = (long long)NB * COUT * HW * HW;
        k_naive<<<(int)((n + 255) / 256), 256, 0, stream>>>(x, w, bias, out, n);
        return;
    }
    unsigned short* wT = (unsigned short*)d_ws;

    k_wxform<<<72, 256, 0, stream>>>(w, wT);
    k_fused<<<NB * HW, 256, 0, stream>>>(x, wT, bias, out);
}

// Round 10
// 96.829 us; speedup vs baseline: 2.1444x; 1.4692x over previous
//
#include <hip/hip_runtime.h>
#include <hip/hip_bf16.h>

typedef __attribute__((ext_vector_type(8))) __bf16 bf16x8;
typedef __attribute__((ext_vector_type(4))) float f32x4;
typedef __attribute__((ext_vector_type(4))) unsigned int u32x4;
typedef unsigned long long ull;

#define NB 16
#define CIN 32
#define COUT 64
#define HW 224
#define HWHW (HW * HW)          // 50176
#define CHW (CIN * HW * HW)     // 1605632

__device__ __forceinline__ unsigned short f2bf(float f) {
    __hip_bfloat16 h = __float2bfloat16(f);
    return __builtin_bit_cast(unsigned short, h);
}

// ---- K1: weight OIHW fp32 -> wT[co][tap][cin] bf16 (64*9*32 = 18432) ----
__global__ void k_wxform(const float* __restrict__ w, unsigned short* __restrict__ wT) {
    int i = blockIdx.x * 256 + threadIdx.x;
    if (i >= COUT * 9 * CIN) return;
    int co = i / (9 * CIN);
    int r  = i % (9 * CIN);
    int tap = r / CIN;
    int c   = r % CIN;
    wT[i] = f2bf(w[(co * CIN + c) * 9 + tap]);
}

// ---- K2: fused conv, register-gather + cross-lane shift dedup.
// One block per (b,h); 4 waves x (64px x 64cout). Each lane loads only its
// CENTER column (8 ch) per input row + 2 group-uniform halo columns; the
// dw=0 / dw=2 shifted fragments are built with ds_bpermute rotations within
// each 16-lane group (edges patched from the adjacent pf register / halo).
// Cuts per-thread VMEM 324 -> ~185. nt stores (bench-faster, r5 vs r9). ----
__global__ __launch_bounds__(256, 3)
void k_fused(const float* __restrict__ x, const unsigned short* __restrict__ wT,
             const float* __restrict__ bias, float* __restrict__ out) {
    int bid = blockIdx.x;
    int wg  = (bid & 7) * 448 + (bid >> 3);   // XCD-chunked swizzle, 3584 = 8*448
    int b = wg / HW, h = wg % HW;
    int wave = threadIdx.x >> 6, lane = threadIdx.x & 63;
    int r = lane & 15;                // A-row (pixel local) / B-col (cout local)
    int q = lane >> 4;
    int chunk = q * 8;                // k sub-chunk (cin)
    const float* xb = x + (ull)b * CHW + (ull)chunk * HWHW;

    // byte-index regs for ds_bpermute rotations within each 16-lane group
    int idxm = (((lane & 48) | ((lane - 1) & 15)) << 2);   // pull from r-1 (wrap)
    int idxp = (((lane & 48) | ((lane + 1) & 15)) << 2);   // pull from r+1 (wrap)
    bool r0  = (r == 0), r15 = (r == 15);

    f32x4 acc[4][4];
    #pragma unroll
    for (int i = 0; i < 4; ++i)
        #pragma unroll
        for (int j = 0; j < 4; ++j) acc[i][j] = (f32x4){0.f, 0.f, 0.f, 0.f};

    #pragma unroll
    for (int dh = 0; dh < 3; ++dh) {
        int hy = h + dh - 1;
        if (hy >= 0 && hy < HW) {         // block-uniform branch (h-pad)
            const float* xrow = xb + (ull)hy * HW;

            // center columns: lane's own px per pf (masked zero past col 223)
            unsigned int own[4][4];
            #pragma unroll
            for (int pf = 0; pf < 4; ++pf) {
                int cpx = wave * 64 + pf * 16 + r;
                bool v = cpx < HW;
                const float* p = xrow + (v ? cpx : HW - 1);
                unsigned int zm = v ? 0xFFFFFFFFu : 0u;
                float f0 = p[0 * HWHW], f1 = p[1 * HWHW];
                float f2 = p[2 * HWHW], f3 = p[3 * HWHW];
                float f4 = p[4 * HWHW], f5 = p[5 * HWHW];
                float f6 = p[6 * HWHW], f7 = p[7 * HWHW];
                own[pf][0] = ((unsigned)f2bf(f0) | ((unsigned)f2bf(f1) << 16)) & zm;
                own[pf][1] = ((unsigned)f2bf(f2) | ((unsigned)f2bf(f3) << 16)) & zm;
                own[pf][2] = ((unsigned)f2bf(f4) | ((unsigned)f2bf(f5) << 16)) & zm;
                own[pf][3] = ((unsigned)f2bf(f6) | ((unsigned)f2bf(f7) << 16)) & zm;
            }
            // halo columns (group-uniform address; masked at w-pad)
            unsigned int hl[4], hr[4];
            {
                int c = wave * 64 - 1;
                bool v = c >= 0;
                const float* p = xrow + (v ? c : 0);
                unsigned int zm = v ? 0xFFFFFFFFu : 0u;
                #pragma unroll
                for (int j = 0; j < 4; ++j) {
                    float f0 = p[(2 * j) * HWHW], f1 = p[(2 * j + 1) * HWHW];
                    hl[j] = ((unsigned)f2bf(f0) | ((unsigned)f2bf(f1) << 16)) & zm;
                }
            }
            {
                int c = wave * 64 + 64;
                bool v = c < HW;
                const float* p = xrow + (v ? c : HW - 1);
                unsigned int zm = v ? 0xFFFFFFFFu : 0u;
                #pragma unroll
                for (int j = 0; j < 4; ++j) {
                    float f0 = p[(2 * j) * HWHW], f1 = p[(2 * j + 1) * HWHW];
                    hr[j] = ((unsigned)f2bf(f0) | ((unsigned)f2bf(f1) << 16)) & zm;
                }
            }

            #pragma unroll
            for (int dw = 0; dw < 3; ++dw) {
                int tap = dh * 3 + dw;
                bf16x8 wf[4];
                #pragma unroll
                for (int cf = 0; cf < 4; ++cf)
                    wf[cf] = *reinterpret_cast<const bf16x8*>(wT + (cf * 16 + r) * 288 + tap * 32 + chunk);
                bf16x8 xf[4];
                #pragma unroll
                for (int pf = 0; pf < 4; ++pf) {
                    u32x4 t;
                    if (dw == 1) {
                        t = (u32x4){own[pf][0], own[pf][1], own[pf][2], own[pf][3]};
                    } else if (dw == 0) {        // col px-1: pull from r-1
                        #pragma unroll
                        for (int j = 0; j < 4; ++j) {
                            int A = __builtin_amdgcn_ds_bpermute(idxm, (int)own[pf][j]);
                            int B = (pf > 0)
                                ? __builtin_amdgcn_ds_bpermute(idxm, (int)own[pf - 1][j])
                                : (int)hl[j];
                            t[j] = (unsigned int)(r0 ? B : A);
                        }
                    } else {                      // col px+1: pull from r+1
                        #pragma unroll
                        for (int j = 0; j < 4; ++j) {
                            int A = __builtin_amdgcn_ds_bpermute(idxp, (int)own[pf][j]);
                            int B = (pf < 3)
                                ? __builtin_amdgcn_ds_bpermute(idxp, (int)own[pf + 1][j])
                                : (int)hr[j];
                            t[j] = (unsigned int)(r15 ? B : A);
                        }
                    }
                    xf[pf] = __builtin_bit_cast(bf16x8, t);
                }
                #pragma unroll
                for (int cf = 0; cf < 4; ++cf)
                    #pragma unroll
                    for (int pf = 0; pf < 4; ++pf)
                        acc[cf][pf] = __builtin_amdgcn_mfma_f32_16x16x32_bf16(xf[pf], wf[cf], acc[cf][pf], 0, 0, 0);
            }
        }
    }

    // epilogue: D row = pixel = q*4+reg, col = cout = lane&15; nt stores
    // (bench A/B r5 vs r9: nt 120.9 vs normal 142.3 despite +88MB WRITE).
    #pragma unroll
    for (int cf = 0; cf < 4; ++cf) {
        int co = cf * 16 + r;
        float bv = bias[co];
        float* orow = out + ((ull)(b * COUT + co) * HW + h) * HW;
        #pragma unroll
        for (int pf = 0; pf < 4; ++pf) {
            int pxb = wave * 64 + pf * 16;
            if (pxb < HW) {                  // frag fully valid or fully masked
                int px0 = pxb + q * 4;
                f32x4 v = acc[cf][pf] + bv;
                __builtin_nontemporal_store(v, reinterpret_cast<f32x4*>(orow + px0));
            }
        }
    }
}

// ---- fallback: naive direct fp32 conv (used only if ws too small) ----
__global__ void k_naive(const float* __restrict__ x, const float* __restrict__ w,
                        const float* __restrict__ bias, float* __restrict__ out, long long n) {
    long long i = (long long)blockIdx.x * 256 + threadIdx.x;
    if (i >= n) return;
    int wc = i % HW; long long t = i / HW;
    int h = t % HW; t /= HW;
    int co = t % COUT; int b = (int)(t / COUT);
    float s = bias[co];
    for (int c = 0; c < CIN; ++c)
        for (int dh = 0; dh < 3; ++dh) {
            int hy = h + dh - 1; if (hy < 0 || hy >= HW) continue;
            for (int dw = 0; dw < 3; ++dw) {
                int wx = wc + dw - 1; if (wx < 0 || wx >= HW) continue;
                s += x[(((long long)b * CIN + c) * HW + hy) * HW + wx] *
                     w[((co * CIN + c) * 3 + dh) * 3 + dw];
            }
        }
    out[i] = s;
}

extern "C" void kernel_launch(void* const* d_in, const int* in_sizes, int n_in,
                              void* d_out, int out_size, void* d_ws, size_t ws_size,
                              hipStream_t stream) {
    const float* x    = (const float*)d_in[0];
    const float* w    = (const float*)d_in[1];
    const float* bias = (const float*)d_in[2];
    float* out = (float*)d_out;

    if (ws_size < (size_t)(COUT * 9 * CIN * 2 + 1024)) {
        long long n = (long long)NB * COUT * HW * HW;
        k_naive<<<(int)((n + 255) / 256), 256, 0, stream>>>(x, w, bias, out, n);
        return;
    }
    unsigned short* wT = (unsigned short*)d_ws;

    k_wxform<<<72, 256, 0, stream>>>(w, wT);
    k_fused<<<NB * HW, 256, 0, stream>>>(x, wT, bias, out);
}